// Round 8
// baseline (263.441 us; speedup 1.0000x reference)
//
#include <hip/hip_runtime.h>
#include <stdint.h>

typedef __attribute__((ext_vector_type(8))) short short8;
typedef __attribute__((ext_vector_type(4))) float f32x4;
typedef __attribute__((ext_vector_type(16))) float f32x16;

#define BH 96
#define T 1024
#define D 256

static __device__ __forceinline__ unsigned short f2bf(float x){
  uint32_t u = __float_as_uint(x);
  uint32_t r = (u + 0x7FFFu + ((u >> 16) & 1u)) >> 16;  // RNE
  return (unsigned short)r;
}

static __device__ __forceinline__ uint32_t cvtpk_bf16(float lo, float hi){
  uint32_t r;
  asm("v_cvt_pk_bf16_f32 %0, %1, %2" : "=v"(r) : "v"(lo), "v"(hi));
  return r;
}

static __device__ __forceinline__ float exp2_fast(float x){
  float r;
  asm("v_exp_f32 %0, %1" : "=v"(r) : "v"(x));
  return r;
}

static __device__ __forceinline__ void gload_lds16(const void* g, void* l){
  __builtin_amdgcn_global_load_lds((const __attribute__((address_space(1))) void*)g,
                                   (__attribute__((address_space(3))) void*)l, 16, 0, 0);
}

// ---------------- Kernel 1: RoPE + (0.25*sqrt(log2e)) scale + bf16 cast
__global__ void k_rope(const float* __restrict__ Q, const float* __restrict__ freqs,
                       unsigned short* __restrict__ QR){
  const float SC = 0.25f * 1.20112241f;   // scores come out in log2 domain
  long idx = (long)blockIdx.x * 256 + threadIdx.x;
  long e = idx * 4;
  int n = (int)(e & (D - 1));
  int t = (int)((e >> 8) & (T - 1));
  float4 q = *(const float4*)(Q + e);
  float f0 = freqs[n];
  float f2 = freqs[n + 2];
  float ph0 = (float)t * f0; ph0 -= floorf(ph0);
  float ph2 = (float)t * f2; ph2 -= floorf(ph2);
  float c0 = __builtin_amdgcn_cosf(ph0), s0 = __builtin_amdgcn_sinf(ph0);
  float c2 = __builtin_amdgcn_cosf(ph2), s2 = __builtin_amdgcn_sinf(ph2);
  float o0 = (q.x * c0 - q.y * s0) * SC;
  float o1 = (q.y * c0 + q.x * s0) * SC;
  float o2 = (q.z * c2 - q.w * s2) * SC;
  float o3 = (q.w * c2 + q.z * s2) * SC;
  ushort4 o;
  o.x = f2bf(o0); o.y = f2bf(o1); o.z = f2bf(o2); o.w = f2bf(o3);
  *(ushort4*)(QR + e) = o;
}

// ---------------- Kernel 2: V [bh][t][n] fp32 -> Vt [bh][n][t] bf16
__global__ void k_transpose(const float* __restrict__ V, unsigned short* __restrict__ Vt){
  __shared__ unsigned short L[64 * 66];
  int bid = blockIdx.x;
  int head = bid >> 6;
  int rem = bid & 63;
  int t0 = (rem & 15) * 64;
  int n0 = (rem >> 4) * 64;
  int tid = threadIdx.x;
  const float* Vh = V + (long)head * T * D;
  unsigned short* Vth = Vt + (long)head * T * D;
  int lr = tid >> 4;
  int lc = (tid & 15) * 4;
#pragma unroll
  for (int i = 0; i < 4; ++i){
    int tl = i * 16 + lr;
    float4 v = *(const float4*)(Vh + (long)(t0 + tl) * D + n0 + lc);
    uint32_t w0 = (uint32_t)f2bf(v.x) | ((uint32_t)f2bf(v.y) << 16);
    uint32_t w1 = (uint32_t)f2bf(v.z) | ((uint32_t)f2bf(v.w) << 16);
    *(uint32_t*)&L[tl * 66 + lc]     = w0;
    *(uint32_t*)&L[tl * 66 + lc + 2] = w1;
  }
  __syncthreads();
  int nr = tid >> 3;
  int t8 = (tid & 7) * 8;
#pragma unroll
  for (int i = 0; i < 2; ++i){
    int n_row = i * 32 + nr;
    unsigned short u[8];
#pragma unroll
    for (int jj = 0; jj < 8; ++jj) u[jj] = L[(t8 + jj) * 66 + n_row];
    uint4 o;
    o.x = (uint32_t)u[0] | ((uint32_t)u[1] << 16);
    o.y = (uint32_t)u[2] | ((uint32_t)u[3] << 16);
    o.z = (uint32_t)u[4] | ((uint32_t)u[5] << 16);
    o.w = (uint32_t)u[6] | ((uint32_t)u[7] << 16);
    *(uint4*)(Vth + (long)(n0 + n_row) * T + t0 + t8) = o;
  }
}

// ---------------- Kernel 3: flash attention, 32x32x16, persistent blocks.
// Grid 256 (1 block/CU), 3 passes/block; triple-buffered LDS (96KB), counted
// vmcnt(8) + raw s_barrier per step (full drain only at pass boundary).
// Pass mapping keeps each XCD's 32 resident blocks on 4 heads (4MB, L2-fit).
__global__ __launch_bounds__(256, 1) void k_flash(const unsigned short* __restrict__ QR,
                                                  const unsigned short* __restrict__ Vt,
                                                  float* __restrict__ Out){
  __shared__ short lds[3][16384];   // [slot][ K:0..8191 | V:8192..16383 ]
  int tid = threadIdx.x;
  int wid = tid >> 6, lane = tid & 63;
  int q31 = lane & 31, h = lane >> 5;

  int cu = blockIdx.x;
  int x = cu & 7;       // XCD (round-robin heuristic)
  int jb = cu >> 3;     // 0..31 within XCD

  // staging source offsets (shorts): same verified maps as R7
  int bK[4], bV[4];
#pragma unroll
  for (int jj = 0; jj < 4; ++jj){
    int i = tid + jj * 256;
    int c = i >> 6, s = i & 63;
    bK[jj] = (s & 31) * 256 + (s >> 5) * 8 + c * 16;
    bV[jj] = ((c >> 1) * 32 + (s & 31)) * 1024 + (c & 1) * 16 + (s >> 5) * 8;
  }

  for (int p = 0; p < 3; ++p){
    int wl = jb + 32 * p;               // 0..95: 4 heads per XCD per pass
    int head = x * 12 + (wl >> 3);
    int qt = wl & 7;
    const unsigned short* qr = QR + (long)head * T * D;
    const unsigned short* vt = Vt + (long)head * T * D;
    int qb = qt * 128 + wid * 32;

    auto stageT = [&](int slot, int tt){
      const unsigned short* sk = qr + (long)tt * 8192;   // 32 keys * 256d
      const unsigned short* sv = vt + tt * 32;
      short* kd = &lds[slot][0];
      short* vd = &lds[slot][8192];
#pragma unroll
      for (int jj = 0; jj < 4; ++jj){
        int i = tid + jj * 256;
        gload_lds16(sk + bK[jj], kd + i * 8);
        gload_lds16(sv + bV[jj], vd + i * 8);
      }
    };

    // Q fragments: lane holds Q[qb+q31][c*16 + h*8 + j]
    short8 qf[16];
#pragma unroll
    for (int c = 0; c < 16; ++c)
      qf[c] = *(const short8*)(qr + (long)(qb + q31) * D + c * 16 + h * 8);

    const f32x16 Zv = {0.f,0.f,0.f,0.f,0.f,0.f,0.f,0.f,0.f,0.f,0.f,0.f,0.f,0.f,0.f,0.f};
    f32x16 acc[8];
#pragma unroll
    for (int i = 0; i < 8; ++i) acc[i] = Zv;
    float m = -3e38f, lsum = 0.f;

    auto computeStep = [&](const short* ldsK, const short* ldsV){
      f32x16 sA = Zv, sB = Zv;
      __builtin_amdgcn_s_setprio(1);
#pragma unroll
      for (int c = 0; c < 8; ++c){
        short8 kf = *(const short8*)&ldsK[c * 512 + lane * 8];
        sA = __builtin_amdgcn_mfma_f32_32x32x16_bf16(kf, qf[c], sA, 0, 0, 0);
      }
#pragma unroll
      for (int c = 8; c < 16; ++c){
        short8 kf = *(const short8*)&ldsK[c * 512 + lane * 8];
        sB = __builtin_amdgcn_mfma_f32_32x32x16_bf16(kf, qf[c], sB, 0, 0, 0);
      }
      __builtin_amdgcn_s_setprio(0);
      f32x16 sc = sA + sB;   // lane's query q31, key (r&3)+8*(r>>2)+4h

      float lm = fmaxf(fmaxf(fmaxf(sc[0], sc[1]), fmaxf(sc[2], sc[3])),
                       fmaxf(fmaxf(sc[4], sc[5]), fmaxf(sc[6], sc[7])));
      lm = fmaxf(lm, fmaxf(fmaxf(fmaxf(sc[8], sc[9]), fmaxf(sc[10], sc[11])),
                           fmaxf(fmaxf(sc[12], sc[13]), fmaxf(sc[14], sc[15]))));
      lm = fmaxf(lm, __shfl_xor(lm, 32));
      if (__any(lm > m + 11.0f)){        // defer-max (log2 units)
        float mn = fmaxf(m, lm);
        float a = exp2_fast(m - mn);
        m = mn;
        lsum *= a;
#pragma unroll
        for (int nb = 0; nb < 8; ++nb) acc[nb] *= a;
      }
      f32x16 pp;
#pragma unroll
      for (int e = 0; e < 16; ++e) pp[e] = exp2_fast(sc[e] - m);
      lsum += (((pp[0]+pp[1])+(pp[2]+pp[3])) + ((pp[4]+pp[5])+(pp[6]+pp[7])))
            + (((pp[8]+pp[9])+(pp[10]+pp[11])) + ((pp[12]+pp[13])+(pp[14]+pp[15])));

      uint32_t X0 = cvtpk_bf16(pp[0],  pp[1]);
      uint32_t X1 = cvtpk_bf16(pp[2],  pp[3]);
      uint32_t Y0 = cvtpk_bf16(pp[4],  pp[5]);
      uint32_t Y1 = cvtpk_bf16(pp[6],  pp[7]);
      uint32_t sX0 = __shfl_xor(X0, 32), sX1 = __shfl_xor(X1, 32);
      uint32_t sY0 = __shfl_xor(Y0, 32), sY1 = __shfl_xor(Y1, 32);
      uint4 f0;
      f0.x = h ? sY0 : X0;
      f0.y = h ? sY1 : X1;
      f0.z = h ? Y0  : sX0;
      f0.w = h ? Y1  : sX1;
      uint32_t Z0 = cvtpk_bf16(pp[8],  pp[9]);
      uint32_t Z1 = cvtpk_bf16(pp[10], pp[11]);
      uint32_t W0 = cvtpk_bf16(pp[12], pp[13]);
      uint32_t W1 = cvtpk_bf16(pp[14], pp[15]);
      uint32_t sZ0 = __shfl_xor(Z0, 32), sZ1 = __shfl_xor(Z1, 32);
      uint32_t sW0 = __shfl_xor(W0, 32), sW1 = __shfl_xor(W1, 32);
      uint4 f1;
      f1.x = h ? sW0 : Z0;
      f1.y = h ? sW1 : Z1;
      f1.z = h ? W0  : sZ0;
      f1.w = h ? W1  : sZ1;
      short8 pF0 = __builtin_bit_cast(short8, f0);
      short8 pF1 = __builtin_bit_cast(short8, f1);

      __builtin_amdgcn_s_setprio(1);
#pragma unroll
      for (int nb = 0; nb < 8; ++nb){
        short8 v0 = *(const short8*)&ldsV[(nb * 2 + 0) * 512 + lane * 8];
        short8 v1 = *(const short8*)&ldsV[(nb * 2 + 1) * 512 + lane * 8];
        acc[nb] = __builtin_amdgcn_mfma_f32_32x32x16_bf16(v0, pF0, acc[nb], 0, 0, 0);
        acc[nb] = __builtin_amdgcn_mfma_f32_32x32x16_bf16(v1, pF1, acc[nb], 0, 0, 0);
      }
      __builtin_amdgcn_s_setprio(0);
    };

    // prologue: stage tiles 0,1 (depth-2 pipeline)
    stageT(0, 0);
    stageT(1, 1);

    int sl = 0, sp = 2;
#pragma unroll 1
    for (int t = 0; t < 31; ++t){
      // tile t ready: only s(t+1)'s 8 loads are newer than s(t)'s
      asm volatile("s_waitcnt vmcnt(8)" ::: "memory");
      asm volatile("s_barrier" ::: "memory");
      if (t + 2 < 32) stageT(sp, t + 2);
      computeStep(&lds[sl][0], &lds[sl][8192]);
      sl = (sl == 2) ? 0 : sl + 1;
      sp = (sp == 2) ? 0 : sp + 1;
    }
    asm volatile("s_waitcnt vmcnt(0)" ::: "memory");
    asm volatile("s_barrier" ::: "memory");
    computeStep(&lds[sl][0], &lds[sl][8192]);

    // epilogue: lane owns query q31; n = nb*32 + rq*8 + h*4 + j
    lsum += __shfl_xor(lsum, 32);
    float r = 1.0f / lsum;
    float* op = Out + (long)head * T * D + (long)(qb + q31) * D + h * 4;
#pragma unroll
    for (int nb = 0; nb < 8; ++nb){
#pragma unroll
      for (int rq = 0; rq < 4; ++rq){
        f32x4 o;
        o.x = acc[nb][rq * 4 + 0] * r;
        o.y = acc[nb][rq * 4 + 1] * r;
        o.z = acc[nb][rq * 4 + 2] * r;
        o.w = acc[nb][rq * 4 + 3] * r;
        *(f32x4*)(op + nb * 32 + rq * 8) = o;
      }
    }
    // protect LDS slots before next pass's prologue staging
    asm volatile("s_barrier" ::: "memory");
  }
}

extern "C" void kernel_launch(void* const* d_in, const int* in_sizes, int n_in,
                              void* d_out, int out_size, void* d_ws, size_t ws_size,
                              hipStream_t stream){
  (void)in_sizes; (void)n_in; (void)out_size; (void)ws_size;
  const float* Q     = (const float*)d_in[0];
  const float* V     = (const float*)d_in[1];
  const float* freqs = (const float*)d_in[2];
  float* Out = (float*)d_out;
  unsigned short* QR = (unsigned short*)d_ws;                  // [96][1024][256] bf16
  unsigned short* Vt = QR + (size_t)BH * T * D;                // [96][256][1024] bf16
  k_rope<<<dim3((BH * T * D) / 4 / 256), dim3(256), 0, stream>>>(Q, freqs, QR);
  k_transpose<<<dim3(BH * 64), dim3(256), 0, stream>>>(V, Vt);
  k_flash<<<dim3(256), dim3(256), 0, stream>>>(QR, Vt, Out);
}

// Round 10
// 214.103 us; speedup vs baseline: 1.2304x; 1.2304x over previous
//
#include <hip/hip_runtime.h>
#include <stdint.h>

typedef __attribute__((ext_vector_type(8))) short short8;
typedef __attribute__((ext_vector_type(4))) float f32x4;
typedef __attribute__((ext_vector_type(4))) _Float16 half4;

#define BH 96
#define T 1024
#define D 256

static __device__ __forceinline__ unsigned short f2bf(float x){
  uint32_t u = __float_as_uint(x);
  uint32_t r = (u + 0x7FFFu + ((u >> 16) & 1u)) >> 16;  // RNE
  return (unsigned short)r;
}

static __device__ __forceinline__ unsigned short f2h(float x){
  _Float16 h = (_Float16)x;
  return __builtin_bit_cast(unsigned short, h);
}

static __device__ __forceinline__ float exp2_fast(float x){
  float r;
  asm("v_exp_f32 %0, %1" : "=v"(r) : "v"(x));
  return r;
}

static __device__ __forceinline__ uint32_t pkrtz(float a, float b){
  return __builtin_bit_cast(uint32_t, __builtin_amdgcn_cvt_pkrtz(a, b));
}

static __device__ __forceinline__ half4 mkhalf4(float a, float b, float c, float d){
  uint32_t lo = pkrtz(a, b);
  uint32_t hi = pkrtz(c, d);
  uint2 u; u.x = lo; u.y = hi;
  return __builtin_bit_cast(half4, u);
}

static __device__ __forceinline__ void gload_lds16(const void* g, void* l){
  __builtin_amdgcn_global_load_lds((const __attribute__((address_space(1))) void*)g,
                                   (__attribute__((address_space(3))) void*)l, 16, 0, 0);
}

// ---------------- Kernel 1: RoPE + (0.25*sqrt(log2e)) scale + bf16 cast
__global__ void k_rope(const float* __restrict__ Q, const float* __restrict__ freqs,
                       unsigned short* __restrict__ QR){
  const float SC = 0.25f * 1.20112241f;   // scores come out in log2 domain
  long idx = (long)blockIdx.x * 256 + threadIdx.x;
  long e = idx * 4;
  int n = (int)(e & (D - 1));
  int t = (int)((e >> 8) & (T - 1));
  float4 q = *(const float4*)(Q + e);
  float f0 = freqs[n];
  float f2 = freqs[n + 2];
  float ph0 = (float)t * f0; ph0 -= floorf(ph0);
  float ph2 = (float)t * f2; ph2 -= floorf(ph2);
  float c0 = __builtin_amdgcn_cosf(ph0), s0 = __builtin_amdgcn_sinf(ph0);
  float c2 = __builtin_amdgcn_cosf(ph2), s2 = __builtin_amdgcn_sinf(ph2);
  float o0 = (q.x * c0 - q.y * s0) * SC;
  float o1 = (q.y * c0 + q.x * s0) * SC;
  float o2 = (q.z * c2 - q.w * s2) * SC;
  float o3 = (q.w * c2 + q.z * s2) * SC;
  ushort4 o;
  o.x = f2bf(o0); o.y = f2bf(o1); o.z = f2bf(o2); o.w = f2bf(o3);
  *(ushort4*)(QR + e) = o;
}

// ---------------- Kernel 2: V [bh][t][n] fp32 -> Vt [bh][n][t] FP16
__global__ void k_transpose(const float* __restrict__ V, unsigned short* __restrict__ Vt){
  __shared__ unsigned short L[64 * 66];
  int bid = blockIdx.x;
  int head = bid >> 6;
  int rem = bid & 63;
  int t0 = (rem & 15) * 64;
  int n0 = (rem >> 4) * 64;
  int tid = threadIdx.x;
  const float* Vh = V + (long)head * T * D;
  unsigned short* Vth = Vt + (long)head * T * D;
  int lr = tid >> 4;
  int lc = (tid & 15) * 4;
#pragma unroll
  for (int i = 0; i < 4; ++i){
    int tl = i * 16 + lr;
    float4 v = *(const float4*)(Vh + (long)(t0 + tl) * D + n0 + lc);
    uint32_t w0 = (uint32_t)f2h(v.x) | ((uint32_t)f2h(v.y) << 16);
    uint32_t w1 = (uint32_t)f2h(v.z) | ((uint32_t)f2h(v.w) << 16);
    *(uint32_t*)&L[tl * 66 + lc]     = w0;
    *(uint32_t*)&L[tl * 66 + lc + 2] = w1;
  }
  __syncthreads();
  int nr = tid >> 3;
  int t8 = (tid & 7) * 8;
#pragma unroll
  for (int i = 0; i < 2; ++i){
    int n_row = i * 32 + nr;
    unsigned short u[8];
#pragma unroll
    for (int jj = 0; jj < 8; ++jj) u[jj] = L[(t8 + jj) * 66 + n_row];
    uint4 o;
    o.x = (uint32_t)u[0] | ((uint32_t)u[1] << 16);
    o.y = (uint32_t)u[2] | ((uint32_t)u[3] << 16);
    o.z = (uint32_t)u[4] | ((uint32_t)u[5] << 16);
    o.w = (uint32_t)u[6] | ((uint32_t)u[7] << 16);
    *(uint4*)(Vth + (long)(n0 + n_row) * T + t0 + t8) = o;
  }
}

// ---------------- Kernel 3: flash attention.
// QK^T: mfma_f32_16x16x32_bf16 (R5-verified maps). PV: mfma_f32_16x16x16f16 —
// QK's C-layout (col=q, row=key) IS the PV B-layout (col=q, k=key): P needs
// ZERO cross-lane redistribution, just 8 cvt_pkrtz per step.
// 4 waves x 32 q-rows (q-tile 128), KTILE=32, double-buffered LDS (64KB).
__global__ __launch_bounds__(256, 2) void k_flash(const unsigned short* __restrict__ QR,
                                                  const unsigned short* __restrict__ Vt,
                                                  float* __restrict__ Out){
  __shared__ short lds[2][16384];   // [buf][ K:0..8191 | V(f16):8192..16383 ]
  int tid = threadIdx.x;
  int wid = tid >> 6, lane = tid & 63;
  int q15 = lane & 15, g = lane >> 4;

  int b = blockIdx.x;
  int x = b & 7, s = b >> 3;
  int qt = s & 7, hg = s >> 3;
  int head = hg * 8 + x;            // XCD-bijective: one head's 8 q-blocks per XCD

  const unsigned short* qr = QR + (long)head * T * D;
  const unsigned short* vt = Vt + (long)head * T * D;
  int qb = qt * 128 + wid * 32;

  // staging source offsets (shorts).
  // K (R5-verified): chunk i -> K[(i>>9)*16 + (i&15)][((i>>6)&7)*32 + ((i>>4)&3)*8]
  // V: chunk i -> Vt[n = i&255][kb + (i>>8)*8]  (LDS slot = i, layout [o4][n256][16B])
  int bK[4], bV[4];
#pragma unroll
  for (int j = 0; j < 4; ++j){
    int i = tid + j * 256;
    bK[j] = (((i >> 9) * 16 + (i & 15)) * 256) + ((i >> 6) & 7) * 32 + ((i >> 4) & 3) * 8;
    bV[j] = (i & 255) * 1024 + (i >> 8) * 8;
  }

  // Q fragments (bf16): lane holds Q[row][c*32 + g*8 + j]
  short8 qfA[8], qfB[8];
#pragma unroll
  for (int c = 0; c < 8; ++c){
    qfA[c] = *(const short8*)(qr + (long)(qb + q15) * D + c * 32 + g * 8);
    qfB[c] = *(const short8*)(qr + (long)(qb + 16 + q15) * D + c * 32 + g * 8);
  }

  f32x4 accA[16], accB[16];
#pragma unroll
  for (int i = 0; i < 16; ++i){
    accA[i] = f32x4{0.f, 0.f, 0.f, 0.f};
    accB[i] = f32x4{0.f, 0.f, 0.f, 0.f};
  }
  float mA = -3e38f, mB = -3e38f, lA = 0.f, lB = 0.f;

  // per-lane V-read base (halves): o = g>>1 (+2 for kg1), n = nc*16+q15, half = g&1
  int vbase = (g >> 1) * 2048 + q15 * 8 + (g & 1) * 4;

  // prologue: stage tile 0 into buf 0
#pragma unroll
  for (int j = 0; j < 4; ++j){
    int i = tid + j * 256;
    gload_lds16(qr + bK[j], &lds[0][i * 8]);
    gload_lds16(vt + bV[j], &lds[0][8192 + i * 8]);
  }
  asm volatile("s_waitcnt vmcnt(0)" ::: "memory");
  __syncthreads();

  int buf = 0;
  for (int kb = 0; kb < T; kb += 32){
    if (kb + 32 < T){
      const unsigned short* sk = qr + (long)(kb + 32) * 256;
      const unsigned short* sv = vt + (kb + 32);
#pragma unroll
      for (int j = 0; j < 4; ++j){
        int i = tid + j * 256;
        gload_lds16(sk + bK[j], &lds[buf ^ 1][i * 8]);
        gload_lds16(sv + bV[j], &lds[buf ^ 1][8192 + i * 8]);
      }
    }
    const short* ldsK = &lds[buf][0];
    const _Float16* ldsVh = (const _Float16*)&lds[buf][8192];

    f32x4 s0a = f32x4{0.f,0.f,0.f,0.f}, s0b = f32x4{0.f,0.f,0.f,0.f};
    f32x4 s1a = f32x4{0.f,0.f,0.f,0.f}, s1b = f32x4{0.f,0.f,0.f,0.f};
    __builtin_amdgcn_s_setprio(1);
#pragma unroll
    for (int c = 0; c < 8; ++c){
      short8 kf0 = *(const short8*)&ldsK[c * 512 + lane * 8];
      short8 kf1 = *(const short8*)&ldsK[4096 + c * 512 + lane * 8];
      s0a = __builtin_amdgcn_mfma_f32_16x16x32_bf16(kf0, qfA[c], s0a, 0, 0, 0);
      s0b = __builtin_amdgcn_mfma_f32_16x16x32_bf16(kf0, qfB[c], s0b, 0, 0, 0);
      s1a = __builtin_amdgcn_mfma_f32_16x16x32_bf16(kf1, qfA[c], s1a, 0, 0, 0);
      s1b = __builtin_amdgcn_mfma_f32_16x16x32_bf16(kf1, qfB[c], s1b, 0, 0, 0);
    }
    __builtin_amdgcn_s_setprio(0);

    // ---- softmax (log2 domain). Defer-max vote on PER-LANE max (no shuffles
    // in steady state); full per-q reduce only inside the rare rescale branch.
    float lmA = fmaxf(fmaxf(fmaxf(s0a.x, s0a.y), fmaxf(s0a.z, s0a.w)),
                      fmaxf(fmaxf(s1a.x, s1a.y), fmaxf(s1a.z, s1a.w)));
    float lmB = fmaxf(fmaxf(fmaxf(s0b.x, s0b.y), fmaxf(s0b.z, s0b.w)),
                      fmaxf(fmaxf(s1b.x, s1b.y), fmaxf(s1b.z, s1b.w)));
    if (__any((lmA > mA + 11.0f) || (lmB > mB + 11.0f))){
      float tmA = fmaxf(lmA, __shfl_xor(lmA, 16)); tmA = fmaxf(tmA, __shfl_xor(tmA, 32));
      float tmB = fmaxf(lmB, __shfl_xor(lmB, 16)); tmB = fmaxf(tmB, __shfl_xor(tmB, 32));
      float mnA = fmaxf(mA, tmA), mnB = fmaxf(mB, tmB);
      float aA = exp2_fast(mA - mnA), aB = exp2_fast(mB - mnB);
      mA = mnA; mB = mnB;
      lA *= aA; lB *= aB;
#pragma unroll
      for (int nc = 0; nc < 16; ++nc){ accA[nc] *= aA; accB[nc] *= aB; }
    }
    float pa0 = exp2_fast(s0a.x - mA), pa1 = exp2_fast(s0a.y - mA);
    float pa2 = exp2_fast(s0a.z - mA), pa3 = exp2_fast(s0a.w - mA);
    float pa4 = exp2_fast(s1a.x - mA), pa5 = exp2_fast(s1a.y - mA);
    float pa6 = exp2_fast(s1a.z - mA), pa7 = exp2_fast(s1a.w - mA);
    float pb0 = exp2_fast(s0b.x - mB), pb1 = exp2_fast(s0b.y - mB);
    float pb2 = exp2_fast(s0b.z - mB), pb3 = exp2_fast(s0b.w - mB);
    float pb4 = exp2_fast(s1b.x - mB), pb5 = exp2_fast(s1b.y - mB);
    float pb6 = exp2_fast(s1b.z - mB), pb7 = exp2_fast(s1b.w - mB);
    lA += ((pa0 + pa1) + (pa2 + pa3)) + ((pa4 + pa5) + (pa6 + pa7));
    lB += ((pb0 + pb1) + (pb2 + pb3)) + ((pb4 + pb5) + (pb6 + pb7));
    // zero-shuffle P: QK C-layout == PV(16x16x16) B-layout
    half4 pA0 = mkhalf4(pa0, pa1, pa2, pa3);   // keys kb+0..15 fragment
    half4 pA1 = mkhalf4(pa4, pa5, pa6, pa7);   // keys kb+16..31
    half4 pB0 = mkhalf4(pb0, pb1, pb2, pb3);
    half4 pB1 = mkhalf4(pb4, pb5, pb6, pb7);

    // ---- PV: O^T form, A = V^T fragment (lane-local 8B from LDS)
    __builtin_amdgcn_s_setprio(1);
#pragma unroll
    for (int nc = 0; nc < 16; ++nc){
      half4 v0 = *(const half4*)&ldsVh[vbase + nc * 128];          // kg=0
      half4 v1 = *(const half4*)&ldsVh[vbase + 4096 + nc * 128];   // kg=1
      accA[nc] = __builtin_amdgcn_mfma_f32_16x16x16f16(v0, pA0, accA[nc], 0, 0, 0);
      accA[nc] = __builtin_amdgcn_mfma_f32_16x16x16f16(v1, pA1, accA[nc], 0, 0, 0);
      accB[nc] = __builtin_amdgcn_mfma_f32_16x16x16f16(v0, pB0, accB[nc], 0, 0, 0);
      accB[nc] = __builtin_amdgcn_mfma_f32_16x16x16f16(v1, pB1, accB[nc], 0, 0, 0);
    }
    __builtin_amdgcn_s_setprio(0);

    asm volatile("s_waitcnt vmcnt(0)" ::: "memory");
    __syncthreads();
    buf ^= 1;
  }

  // epilogue: O^T acc -> lane owns query q15 (per sub-tile); float4 stores
  lA += __shfl_xor(lA, 16); lA += __shfl_xor(lA, 32);
  lB += __shfl_xor(lB, 16); lB += __shfl_xor(lB, 32);
  float rA = 1.0f / lA, rB = 1.0f / lB;
  float* opA = Out + (long)head * T * D + (long)(qb + q15) * D + g * 4;
  float* opB = opA + 16 * D;
#pragma unroll
  for (int nc = 0; nc < 16; ++nc){
    f32x4 oa = accA[nc] * rA;
    f32x4 ob = accB[nc] * rB;
    *(f32x4*)(opA + nc * 16) = oa;
    *(f32x4*)(opB + nc * 16) = ob;
  }
}

extern "C" void kernel_launch(void* const* d_in, const int* in_sizes, int n_in,
                              void* d_out, int out_size, void* d_ws, size_t ws_size,
                              hipStream_t stream){
  (void)in_sizes; (void)n_in; (void)out_size; (void)ws_size;
  const float* Q     = (const float*)d_in[0];
  const float* V     = (const float*)d_in[1];
  const float* freqs = (const float*)d_in[2];
  float* Out = (float*)d_out;
  unsigned short* QR = (unsigned short*)d_ws;                  // [96][1024][256] bf16
  unsigned short* Vt = QR + (size_t)BH * T * D;                // [96][256][1024] f16
  k_rope<<<dim3((BH * T * D) / 4 / 256), dim3(256), 0, stream>>>(Q, freqs, QR);
  k_transpose<<<dim3(BH * 64), dim3(256), 0, stream>>>(V, Vt);
  k_flash<<<dim3(BH * 8), dim3(256), 0, stream>>>(QR, Vt, Out);
}